// Round 2
// baseline (9084.463 us; speedup 1.0000x reference)
//
#include <hip/hip_runtime.h>
#include <math.h>

#define Bsz 1024
#define Lsz 50
#define Esz 256
#define Hsz 256
#define NEGV (-1e9f)

// ============================================================
// init: copy decoder_input -> dec buffer, zero the mask
// ============================================================
__global__ void init_kernel(const float* __restrict__ dec0,
                            float* __restrict__ dec,
                            int* __restrict__ mask)
{
    int i = blockIdx.x * 256 + threadIdx.x;
    dec[i] = dec0[i];
    if (i < Bsz * Lsz) mask[i] = 0;
}

// ============================================================
// transpose the two Wq matrices once: WqT[k][n] = Wq[n][k]
// grid (256, 2) x 256 threads
// ============================================================
__global__ void transpose_wq(const float* __restrict__ WqGl, const float* __restrict__ WqPt,
                             float* __restrict__ WqGlT, float* __restrict__ WqPtT)
{
    int k = blockIdx.x;
    int n = threadIdx.x;
    if (blockIdx.y == 0) WqGlT[k * 256 + n] = WqGl[n * 256 + k];
    else                 WqPtT[k * 256 + n] = WqPt[n * 256 + k];
}

// ============================================================
// e-projection GEMM: Eo[b,l,h] = sum_k context[l,b,k]*W[h,k] + bias[h]
// grid: (L*B/64, H/64), one-time
// ============================================================
__global__ __launch_bounds__(256) void eproj_kernel(const float* __restrict__ A,
                                                    const float* __restrict__ W,
                                                    const float* __restrict__ bias,
                                                    float* __restrict__ Eo)
{
    __shared__ __align__(16) float As[16][64];
    __shared__ __align__(16) float Bs[16][64];
    const int tid = threadIdx.x;
    const int tx = tid & 15, ty = tid >> 4;
    const int ml = tid >> 2;
    const int kb = (tid & 3) << 2;
    const int m0 = blockIdx.x * 64, n0 = blockIdx.y * 64;
    const int K = Hsz;
    float acc[4][4] = {};
    for (int k0 = 0; k0 < K; k0 += 16) {
        float4 a4 = *(const float4*)(A + (size_t)(m0 + ml) * K + k0 + kb);
        float4 b4 = *(const float4*)(W + (size_t)(n0 + ml) * K + k0 + kb);
        As[kb+0][ml] = a4.x; As[kb+1][ml] = a4.y; As[kb+2][ml] = a4.z; As[kb+3][ml] = a4.w;
        Bs[kb+0][ml] = b4.x; Bs[kb+1][ml] = b4.y; Bs[kb+2][ml] = b4.z; Bs[kb+3][ml] = b4.w;
        __syncthreads();
#pragma unroll
        for (int kk = 0; kk < 16; kk++) {
            float4 av = *(const float4*)(&As[kk][ty << 2]);
            float4 bv = *(const float4*)(&Bs[kk][tx << 2]);
            float a_[4] = {av.x, av.y, av.z, av.w};
            float b_[4] = {bv.x, bv.y, bv.z, bv.w};
#pragma unroll
            for (int i = 0; i < 4; i++)
#pragma unroll
                for (int j = 0; j < 4; j++) acc[i][j] = fmaf(a_[i], b_[j], acc[i][j]);
        }
        __syncthreads();
    }
#pragma unroll
    for (int i = 0; i < 4; i++) {
        int m = m0 + (ty << 2) + i;
        int bb = m & (Bsz - 1);
        int ll = m >> 10;
#pragma unroll
        for (int j = 0; j < 4; j++) {
            int n = n0 + (tx << 2) + j;
            Eo[(size_t)bb * Lsz * Hsz + (size_t)ll * Hsz + n] = acc[i][j] + bias[n];
        }
    }
}

// ============================================================
// K1: fused LSTM  G = [x;h]·[Wih;Whh]^T  + gate nonlinearity epilogue.
// Output tile: 64 rows x (16 hidden units x 4 gates).  Column permutation
// p = hcol*4 + gate so each thread's 4 acc columns are the 4 gates of one
// hidden unit.  grid (16,16) x 256 thr, global->LDS prefetch pipeline.
// ============================================================
__global__ __launch_bounds__(256) void lstm_fused(
    const float* __restrict__ dec, const float* __restrict__ hprev,
    const float* __restrict__ cin,
    const float* __restrict__ Wih, const float* __restrict__ Whh,
    const float* __restrict__ bih, const float* __restrict__ bhh,
    float* __restrict__ hout, float* __restrict__ cout)
{
    __shared__ __align__(16) float As[16][64];
    __shared__ __align__(16) float Bs[16][64];
    const int tid = threadIdx.x;
    const int tx = tid & 15, ty = tid >> 4;
    const int ml = tid >> 2;
    const int kb = (tid & 3) << 2;
    const int m0 = blockIdx.x * 64;
    const int hh0 = blockIdx.y * 16;
    const int wrow = ((ml >> 4) << 8) + hh0 + (ml & 15);   // gate*256 + hh
    const int pcol = ((ml & 15) << 2) + (ml >> 4);         // hcol*4 + gate

    float4 a4 = *(const float4*)(dec + (size_t)(m0 + ml) * 256 + kb);
    float4 b4 = *(const float4*)(Wih + (size_t)wrow * 256 + kb);

    float acc[4][4] = {};
    for (int k0 = 0; k0 < 512; k0 += 16) {
        As[kb+0][ml] = a4.x; As[kb+1][ml] = a4.y; As[kb+2][ml] = a4.z; As[kb+3][ml] = a4.w;
        Bs[kb+0][pcol] = b4.x; Bs[kb+1][pcol] = b4.y; Bs[kb+2][pcol] = b4.z; Bs[kb+3][pcol] = b4.w;
        __syncthreads();
        int k1 = k0 + 16;
        if (k1 < 512) {
            const float* A = (k1 < 256) ? dec : hprev;
            const float* W = (k1 < 256) ? Wih : Whh;
            int kk0 = k1 & 255;
            a4 = *(const float4*)(A + (size_t)(m0 + ml) * 256 + kk0 + kb);
            b4 = *(const float4*)(W + (size_t)wrow * 256 + kk0 + kb);
        }
#pragma unroll
        for (int kk = 0; kk < 16; kk++) {
            float4 av = *(const float4*)(&As[kk][ty << 2]);
            float4 bv = *(const float4*)(&Bs[kk][tx << 2]);
            float a_[4] = {av.x, av.y, av.z, av.w};
            float b_[4] = {bv.x, bv.y, bv.z, bv.w};
#pragma unroll
            for (int i = 0; i < 4; i++)
#pragma unroll
                for (int j = 0; j < 4; j++) acc[i][j] = fmaf(a_[i], b_[j], acc[i][j]);
        }
        __syncthreads();
    }

    const int hh = hh0 + tx;
    const float bi0 = bih[hh]       + bhh[hh];
    const float bf  = bih[256 + hh] + bhh[256 + hh];
    const float bg  = bih[512 + hh] + bhh[512 + hh];
    const float bo  = bih[768 + hh] + bhh[768 + hh];
#pragma unroll
    for (int i = 0; i < 4; i++) {
        int m = m0 + (ty << 2) + i;
        float gi = acc[i][0] + bi0;
        float gf = acc[i][1] + bf;
        float gc = acc[i][2] + bg;
        float go = acc[i][3] + bo;
        float ii = 1.0f / (1.0f + expf(-gi));
        float ff = 1.0f / (1.0f + expf(-gf));
        float oo = 1.0f / (1.0f + expf(-go));
        float c2 = ff * cin[(size_t)m * 256 + hh] + ii * tanhf(gc);
        hout[(size_t)m * 256 + hh] = oo * tanhf(c2);
        cout[(size_t)m * 256 + hh] = c2;
    }
}

// ============================================================
// K2: per-row fused glimpse-q matvec -> glimpse attention ->
// pointer-q matvec -> pointer attention + argmax + mask + gather.
// 512 blocks x 256 threads, 2 batch rows per block.
// ============================================================
__global__ __launch_bounds__(256) void step_fused(
    const float* __restrict__ h,
    const float* __restrict__ WqGlT, const float* __restrict__ glbq,
    const float* __restrict__ e_gl, const float* __restrict__ glv,
    const float* __restrict__ WqPtT, const float* __restrict__ ptbq,
    const float* __restrict__ e_pt, const float* __restrict__ ptv,
    int* __restrict__ mask, float* __restrict__ out, int t,
    float* __restrict__ dec, const float* __restrict__ emb)
{
    __shared__ float eb_s[Lsz * 256];     // 51.2 KB: staged e row for mix reuse
    __shared__ float h2_s[2][256];
    __shared__ float g2_s[2][256];
    __shared__ float part[Lsz][4];
    __shared__ float logit_s[Lsz];
    __shared__ float p_s[Lsz];
    __shared__ float scal[2];
    __shared__ int sel_s;

    const int tid = threadIdx.x;
    const int lane = tid & 63, wid = tid >> 6;
    const int b0 = blockIdx.x * 2;

    h2_s[0][tid] = h[(size_t)b0 * 256 + tid];
    h2_s[1][tid] = h[(size_t)(b0 + 1) * 256 + tid];
    __syncthreads();

    // ---- glimpse query matvec (2 rows share each weight load) ----
    float q0 = glbq[tid], q1 = q0;
#pragma unroll 8
    for (int k = 0; k < 256; k++) {
        float w = WqGlT[(size_t)k * 256 + tid];
        q0 = fmaf(h2_s[0][k], w, q0);
        q1 = fmaf(h2_s[1][k], w, q1);
    }
    const float vgl = glv[tid];

    // ---- glimpse attention, row-sequential ----
    for (int r = 0; r < 2; r++) {
        const int b = b0 + r;
        const float qr = r ? q1 : q0;
        const float* erow = e_gl + (size_t)b * Lsz * 256 + tid;
#pragma unroll
        for (int l = 0; l < Lsz; l++) {
            float ev = erow[(size_t)l * 256];
            eb_s[l * 256 + tid] = ev;
            float x = tanhf(qr + ev) * vgl;
#pragma unroll
            for (int o = 32; o > 0; o >>= 1) x += __shfl_xor(x, o, 64);
            if (lane == 0) part[l][wid] = x;
        }
        __syncthreads();
        if (tid < Lsz) {
            float u = part[tid][0] + part[tid][1] + part[tid][2] + part[tid][3];
            float logit = u;
            if (mask[b * Lsz + tid]) logit = NEGV;
            logit_s[tid] = logit;
        }
        __syncthreads();
        if (tid == 0) {
            float m = logit_s[0];
#pragma unroll
            for (int l = 1; l < Lsz; l++) m = fmaxf(m, logit_s[l]);
            float den = 0.0f;
#pragma unroll
            for (int l = 0; l < Lsz; l++) {
                float pl = expf(logit_s[l] - m);
                p_s[l] = pl;
                den += pl;
            }
            scal[1] = den;
        }
        __syncthreads();
        const float inv = 1.0f / scal[1];
        float acc = 0.0f;
#pragma unroll
        for (int l = 0; l < Lsz; l++) acc = fmaf(p_s[l], eb_s[l * 256 + tid], acc);
        g2_s[r][tid] = acc * inv;
        __syncthreads();   // protect eb_s/part reuse by next row
    }

    // ---- pointer query matvec ----
    float p0 = ptbq[tid], p1 = p0;
#pragma unroll 8
    for (int k = 0; k < 256; k++) {
        float w = WqPtT[(size_t)k * 256 + tid];
        p0 = fmaf(g2_s[0][k], w, p0);
        p1 = fmaf(g2_s[1][k], w, p1);
    }
    const float vpt = ptv[tid];

    // ---- pointer attention + decode, row-sequential ----
    for (int r = 0; r < 2; r++) {
        const int b = b0 + r;
        const float pr = r ? p1 : p0;
        const float* erow = e_pt + (size_t)b * Lsz * 256 + tid;
#pragma unroll
        for (int l = 0; l < Lsz; l++) {
            float ev = erow[(size_t)l * 256];
            float x = tanhf(pr + ev) * vpt;
#pragma unroll
            for (int o = 32; o > 0; o >>= 1) x += __shfl_xor(x, o, 64);
            if (lane == 0) part[l][wid] = x;
        }
        __syncthreads();
        if (tid < Lsz) {
            float u = part[tid][0] + part[tid][1] + part[tid][2] + part[tid][3];
            float logit = 10.0f * tanhf(u);
            if (mask[b * Lsz + tid]) logit = NEGV;
            logit_s[tid] = logit;
        }
        __syncthreads();
        if (tid == 0) {
            float m = logit_s[0];
#pragma unroll
            for (int l = 1; l < Lsz; l++) m = fmaxf(m, logit_s[l]);
            float den = 0.0f;
#pragma unroll
            for (int l = 0; l < Lsz; l++) den += expf(logit_s[l] - m);
            scal[0] = m; scal[1] = den;
            float best = logit_s[0]; int bi = 0;
#pragma unroll
            for (int l = 1; l < Lsz; l++)
                if (logit_s[l] > best) { best = logit_s[l]; bi = l; }
            sel_s = bi;
            out[(size_t)Bsz * Lsz * Lsz + (size_t)b * Lsz + t] = (float)bi;
            mask[b * Lsz + bi] = 1;
            int all = 1;
            for (int l = 0; l < Lsz; l++) all &= mask[b * Lsz + l];
            if (all) mask[b * Lsz + Lsz - 1] = 0;
        }
        __syncthreads();
        const float lse = scal[0] + logf(scal[1]);
        if (tid < Lsz)
            out[(size_t)b * Lsz * Lsz + (size_t)t * Lsz + tid] = logit_s[tid] - lse;
        const int s = sel_s;
        dec[(size_t)b * 256 + tid] = emb[(size_t)s * Bsz * 256 + (size_t)b * 256 + tid];
        __syncthreads();   // part/logit reuse by next row
    }
}

// ============================================================
extern "C" void kernel_launch(void* const* d_in, const int* in_sizes, int n_in,
                              void* d_out, int out_size, void* d_ws, size_t ws_size,
                              hipStream_t stream) {
    const float* decoder_input = (const float*)d_in[0];
    const float* emb           = (const float*)d_in[1];   // [L,B,E]
    const float* h0            = (const float*)d_in[2];
    const float* c0            = (const float*)d_in[3];
    const float* context       = (const float*)d_in[4];   // [L,B,H]
    const float* Wih    = (const float*)d_in[6];
    const float* Whh    = (const float*)d_in[7];
    const float* bih    = (const float*)d_in[8];
    const float* bhh    = (const float*)d_in[9];
    const float* glWq   = (const float*)d_in[10];
    const float* glbq   = (const float*)d_in[11];
    const float* glWref = (const float*)d_in[12];
    const float* glbref = (const float*)d_in[13];
    const float* glv    = (const float*)d_in[14];
    const float* ptWq   = (const float*)d_in[15];
    const float* ptbq   = (const float*)d_in[16];
    const float* ptWref = (const float*)d_in[17];
    const float* ptbref = (const float*)d_in[18];
    const float* ptv    = (const float*)d_in[19];

    float* out = (float*)d_out;

    // workspace layout (floats)
    float* ws    = (float*)d_ws;
    float* e_gl  = ws;                                    // [B,L,H]
    float* e_pt  = e_gl + (size_t)Bsz * Lsz * Hsz;        // [B,L,H]
    float* WqGlT = e_pt + (size_t)Bsz * Lsz * Hsz;        // [H,H]
    float* WqPtT = WqGlT + (size_t)Hsz * Hsz;
    float* hb0   = WqPtT + (size_t)Hsz * Hsz;
    float* hb1   = hb0 + (size_t)Bsz * Hsz;
    float* cb0   = hb1 + (size_t)Bsz * Hsz;
    float* cb1   = cb0 + (size_t)Bsz * Hsz;
    float* dec   = cb1 + (size_t)Bsz * Hsz;
    int*   mask  = (int*)(dec + (size_t)Bsz * Esz);       // [B,L]

    float* hbuf[2] = {hb0, hb1};
    float* cbuf[2] = {cb0, cb1};

    init_kernel<<<dim3(Bsz), dim3(256), 0, stream>>>(decoder_input, dec, mask);
    transpose_wq<<<dim3(256, 2), dim3(256), 0, stream>>>(glWq, ptWq, WqGlT, WqPtT);

    dim3 ge(Lsz * Bsz / 64, Hsz / 64);
    eproj_kernel<<<ge, dim3(256), 0, stream>>>(context, glWref, glbref, e_gl);
    eproj_kernel<<<ge, dim3(256), 0, stream>>>(context, ptWref, ptbref, e_pt);

    for (int t = 0; t < Lsz; t++) {
        const float* hin = (t == 0) ? h0 : hbuf[(t + 1) & 1];
        const float* cin = (t == 0) ? c0 : cbuf[(t + 1) & 1];
        float* hout = hbuf[t & 1];
        float* cout = cbuf[t & 1];

        lstm_fused<<<dim3(16, 16), dim3(256), 0, stream>>>(
            dec, hin, cin, Wih, Whh, bih, bhh, hout, cout);

        step_fused<<<dim3(512), dim3(256), 0, stream>>>(
            hout, WqGlT, glbq, e_gl, glv, WqPtT, ptbq, e_pt, ptv,
            mask, out, t, dec, emb);
    }
}

// Round 3
// 4579.441 us; speedup vs baseline: 1.9837x; 1.9837x over previous
//
#include <hip/hip_runtime.h>
#include <math.h>

#define Bsz 1024
#define Lsz 50
#define Esz 256
#define Hsz 256
#define NEGV (-1e9f)

// ============================================================
// init: copy decoder_input -> dec buffer, zero the mask
// ============================================================
__global__ void init_kernel(const float* __restrict__ dec0,
                            float* __restrict__ dec,
                            int* __restrict__ mask)
{
    int i = blockIdx.x * 256 + threadIdx.x;
    dec[i] = dec0[i];
    if (i < Bsz * Lsz) mask[i] = 0;
}

// ============================================================
// transpose the two Wq matrices once: WqT[k][n] = Wq[n][k]
// ============================================================
__global__ void transpose_wq(const float* __restrict__ WqGl, const float* __restrict__ WqPt,
                             float* __restrict__ WqGlT, float* __restrict__ WqPtT)
{
    int k = blockIdx.x;
    int n = threadIdx.x;
    if (blockIdx.y == 0) WqGlT[k * 256 + n] = WqGl[n * 256 + k];
    else                 WqPtT[k * 256 + n] = WqPt[n * 256 + k];
}

// ============================================================
// e-projection GEMM (one-time): Eo[b,l,h] = sum_k context[l,b,k]*W[h,k]+bias[h]
// ============================================================
__global__ __launch_bounds__(256) void eproj_kernel(const float* __restrict__ A,
                                                    const float* __restrict__ W,
                                                    const float* __restrict__ bias,
                                                    float* __restrict__ Eo)
{
    __shared__ __align__(16) float As[16][64];
    __shared__ __align__(16) float Bs[16][64];
    const int tid = threadIdx.x;
    const int tx = tid & 15, ty = tid >> 4;
    const int ml = tid >> 2;
    const int kb = (tid & 3) << 2;
    const int m0 = blockIdx.x * 64, n0 = blockIdx.y * 64;
    const int K = Hsz;
    float acc[4][4] = {};
    for (int k0 = 0; k0 < K; k0 += 16) {
        float4 a4 = *(const float4*)(A + (size_t)(m0 + ml) * K + k0 + kb);
        float4 b4 = *(const float4*)(W + (size_t)(n0 + ml) * K + k0 + kb);
        As[kb+0][ml] = a4.x; As[kb+1][ml] = a4.y; As[kb+2][ml] = a4.z; As[kb+3][ml] = a4.w;
        Bs[kb+0][ml] = b4.x; Bs[kb+1][ml] = b4.y; Bs[kb+2][ml] = b4.z; Bs[kb+3][ml] = b4.w;
        __syncthreads();
#pragma unroll
        for (int kk = 0; kk < 16; kk++) {
            float4 av = *(const float4*)(&As[kk][ty << 2]);
            float4 bv = *(const float4*)(&Bs[kk][tx << 2]);
            float a_[4] = {av.x, av.y, av.z, av.w};
            float b_[4] = {bv.x, bv.y, bv.z, bv.w};
#pragma unroll
            for (int i = 0; i < 4; i++)
#pragma unroll
                for (int j = 0; j < 4; j++) acc[i][j] = fmaf(a_[i], b_[j], acc[i][j]);
        }
        __syncthreads();
    }
#pragma unroll
    for (int i = 0; i < 4; i++) {
        int m = m0 + (ty << 2) + i;
        int bb = m & (Bsz - 1);
        int ll = m >> 10;
#pragma unroll
        for (int j = 0; j < 4; j++) {
            int n = n0 + (tx << 2) + j;
            Eo[(size_t)bb * Lsz * Hsz + (size_t)ll * Hsz + n] = acc[i][j] + bias[n];
        }
    }
}

// ============================================================
// K1: fused LSTM  G = [x;h]·[Wih;Whh]^T + gate epilogue (unchanged, passing)
// ============================================================
__global__ __launch_bounds__(256) void lstm_fused(
    const float* __restrict__ dec, const float* __restrict__ hprev,
    const float* __restrict__ cin,
    const float* __restrict__ Wih, const float* __restrict__ Whh,
    const float* __restrict__ bih, const float* __restrict__ bhh,
    float* __restrict__ hout, float* __restrict__ cout)
{
    __shared__ __align__(16) float As[16][64];
    __shared__ __align__(16) float Bs[16][64];
    const int tid = threadIdx.x;
    const int tx = tid & 15, ty = tid >> 4;
    const int ml = tid >> 2;
    const int kb = (tid & 3) << 2;
    const int m0 = blockIdx.x * 64;
    const int hh0 = blockIdx.y * 16;
    const int wrow = ((ml >> 4) << 8) + hh0 + (ml & 15);   // gate*256 + hh
    const int pcol = ((ml & 15) << 2) + (ml >> 4);         // hcol*4 + gate

    float4 a4 = *(const float4*)(dec + (size_t)(m0 + ml) * 256 + kb);
    float4 b4 = *(const float4*)(Wih + (size_t)wrow * 256 + kb);

    float acc[4][4] = {};
    for (int k0 = 0; k0 < 512; k0 += 16) {
        As[kb+0][ml] = a4.x; As[kb+1][ml] = a4.y; As[kb+2][ml] = a4.z; As[kb+3][ml] = a4.w;
        Bs[kb+0][pcol] = b4.x; Bs[kb+1][pcol] = b4.y; Bs[kb+2][pcol] = b4.z; Bs[kb+3][pcol] = b4.w;
        __syncthreads();
        int k1 = k0 + 16;
        if (k1 < 512) {
            const float* A = (k1 < 256) ? dec : hprev;
            const float* W = (k1 < 256) ? Wih : Whh;
            int kk0 = k1 & 255;
            a4 = *(const float4*)(A + (size_t)(m0 + ml) * 256 + kk0 + kb);
            b4 = *(const float4*)(W + (size_t)wrow * 256 + kk0 + kb);
        }
#pragma unroll
        for (int kk = 0; kk < 16; kk++) {
            float4 av = *(const float4*)(&As[kk][ty << 2]);
            float4 bv = *(const float4*)(&Bs[kk][tx << 2]);
            float a_[4] = {av.x, av.y, av.z, av.w};
            float b_[4] = {bv.x, bv.y, bv.z, bv.w};
#pragma unroll
            for (int i = 0; i < 4; i++)
#pragma unroll
                for (int j = 0; j < 4; j++) acc[i][j] = fmaf(a_[i], b_[j], acc[i][j]);
        }
        __syncthreads();
    }

    const int hh = hh0 + tx;
    const float bi0 = bih[hh]       + bhh[hh];
    const float bf  = bih[256 + hh] + bhh[256 + hh];
    const float bg  = bih[512 + hh] + bhh[512 + hh];
    const float bo  = bih[768 + hh] + bhh[768 + hh];
#pragma unroll
    for (int i = 0; i < 4; i++) {
        int m = m0 + (ty << 2) + i;
        float gi = acc[i][0] + bi0;
        float gf = acc[i][1] + bf;
        float gc = acc[i][2] + bg;
        float go = acc[i][3] + bo;
        float ii = 1.0f / (1.0f + expf(-gi));
        float ff = 1.0f / (1.0f + expf(-gf));
        float oo = 1.0f / (1.0f + expf(-go));
        float c2 = ff * cin[(size_t)m * 256 + hh] + ii * tanhf(gc);
        hout[(size_t)m * 256 + hh] = oo * tanhf(c2);
        cout[(size_t)m * 256 + hh] = c2;
    }
}

// ============================================================
// K2/K3: attention, one block per batch row, 256 threads, tiny LDS.
//  phase 1: q[tid] = bq[tid] + sum_k h_s[k]*WqT[k][tid]
//  phase 2: u_l = sum_h v_h tanh(q_h + e[l][h]) — wave w handles l=4p+w,
//           lane = h-quad, float4 loads, 64-lane butterfly reduce
//  phase 3 (wave-parallel): softmax over L
//  PTR=false: g_out[h] = sum_l p_l e[l][h] (l-ordered re-read, L2-hot)
//  PTR=true : log_p write, argmax (first-index ties), mask update, gather
// ============================================================
template<bool PTR>
__global__ __launch_bounds__(256) void attn_kernel(
    const float* __restrict__ hq, const float* __restrict__ WqT,
    const float* __restrict__ bq,
    const float* __restrict__ e, const float* __restrict__ v,
    int* __restrict__ mask,
    float* __restrict__ g_out, float* __restrict__ out, int t,
    float* __restrict__ dec, const float* __restrict__ emb)
{
    __shared__ float h_s[256];
    __shared__ __align__(16) float q_s[256];
    __shared__ float u_s[64];
    __shared__ float p_s[64];
    __shared__ int sel_s;

    const int tid = threadIdx.x;
    const int lane = tid & 63, wave = tid >> 6;
    const int b = blockIdx.x;

    h_s[tid] = hq[(size_t)b * 256 + tid];
    __syncthreads();

    // ---- phase 1: query matvec ----
    float q = bq[tid];
#pragma unroll 8
    for (int k = 0; k < 256; k++)
        q = fmaf(h_s[k], WqT[(size_t)k * 256 + tid], q);
    q_s[tid] = q;
    __syncthreads();

    const float4 q4 = ((const float4*)q_s)[lane];
    const float4 v4 = ((const float4*)v)[lane];
    const float* eb = e + (size_t)b * Lsz * 256;

    // ---- phase 2: u over l (wave w: l = 4p+w) ----
#pragma unroll
    for (int lp = 0; lp < 13; lp++) {
        const int l = lp * 4 + wave;
        float x = 0.0f;
        if (l < Lsz) {
            float4 e4 = *(const float4*)(eb + (size_t)l * 256 + (lane << 2));
            x = v4.x * tanhf(q4.x + e4.x);
            x += v4.y * tanhf(q4.y + e4.y);
            x += v4.z * tanhf(q4.z + e4.z);
            x += v4.w * tanhf(q4.w + e4.w);
        }
#pragma unroll
        for (int o = 32; o > 0; o >>= 1) x += __shfl_xor(x, o, 64);
        if (lane == 0 && l < Lsz) u_s[l] = x;
    }
    __syncthreads();

    // ---- phase 3: lane-parallel softmax (+ decode for PTR) in wave 0 ----
    if (wave == 0) {
        const int l = lane;
        const int ml = (l < Lsz) ? mask[b * Lsz + l] : 0;
        float logit;
        if (l < Lsz) {
            float u = u_s[l];
            logit = PTR ? 10.0f * tanhf(u) : u;
            if (ml) logit = NEGV;
        } else logit = -1e30f;

        float m = logit;
#pragma unroll
        for (int o = 32; o > 0; o >>= 1) m = fmaxf(m, __shfl_xor(m, o, 64));
        float ex = (l < Lsz) ? expf(logit - m) : 0.0f;
        float den = ex;
#pragma unroll
        for (int o = 32; o > 0; o >>= 1) den += __shfl_xor(den, o, 64);

        if (!PTR) {
            if (l < Lsz) p_s[l] = ex / den;
        } else {
            // argmax with first-index tie-break
            float av = logit; int ai = (l < Lsz) ? l : 63;
#pragma unroll
            for (int o = 32; o > 0; o >>= 1) {
                float ov = __shfl_xor(av, o, 64);
                int   oi = __shfl_xor(ai, o, 64);
                if (ov > av || (ov == av && oi < ai)) { av = ov; ai = oi; }
            }
            const float lse = m + logf(den);
            if (l < Lsz)
                out[(size_t)b * Lsz * Lsz + (size_t)t * Lsz + l] = logit - lse;
            if (l == 0) {
                out[(size_t)Bsz * Lsz * Lsz + (size_t)b * Lsz + t] = (float)ai;
                sel_s = ai;
            }
            // mask update + all-true fixup
            int newm = ml | (l == ai);
            unsigned long long bal = __ballot(l >= Lsz ? 1 : newm);
            int all = (bal == 0xFFFFFFFFFFFFFFFFull);
            if (l < Lsz) mask[b * Lsz + l] = (all && l == Lsz - 1) ? 0 : newm;
        }
    }
    __syncthreads();

    if (!PTR) {
        // ---- glimpse mix: exact l-order, row is L2-hot ----
        float acc = 0.0f;
        const float* ebh = eb + tid;
#pragma unroll
        for (int l = 0; l < Lsz; l++)
            acc = fmaf(p_s[l], ebh[(size_t)l * 256], acc);
        g_out[(size_t)b * 256 + tid] = acc;
    } else {
        const int s = sel_s;
        dec[(size_t)b * 256 + tid] = emb[(size_t)s * Bsz * 256 + (size_t)b * 256 + tid];
    }
}

// ============================================================
extern "C" void kernel_launch(void* const* d_in, const int* in_sizes, int n_in,
                              void* d_out, int out_size, void* d_ws, size_t ws_size,
                              hipStream_t stream) {
    const float* decoder_input = (const float*)d_in[0];
    const float* emb           = (const float*)d_in[1];   // [L,B,E]
    const float* h0            = (const float*)d_in[2];
    const float* c0            = (const float*)d_in[3];
    const float* context       = (const float*)d_in[4];   // [L,B,H]
    const float* Wih    = (const float*)d_in[6];
    const float* Whh    = (const float*)d_in[7];
    const float* bih    = (const float*)d_in[8];
    const float* bhh    = (const float*)d_in[9];
    const float* glWq   = (const float*)d_in[10];
    const float* glbq   = (const float*)d_in[11];
    const float* glWref = (const float*)d_in[12];
    const float* glbref = (const float*)d_in[13];
    const float* glv    = (const float*)d_in[14];
    const float* ptWq   = (const float*)d_in[15];
    const float* ptbq   = (const float*)d_in[16];
    const float* ptWref = (const float*)d_in[17];
    const float* ptbref = (const float*)d_in[18];
    const float* ptv    = (const float*)d_in[19];

    float* out = (float*)d_out;

    // workspace layout (floats)
    float* ws    = (float*)d_ws;
    float* e_gl  = ws;                                    // [B,L,H]
    float* e_pt  = e_gl + (size_t)Bsz * Lsz * Hsz;        // [B,L,H]
    float* WqGlT = e_pt + (size_t)Bsz * Lsz * Hsz;        // [H,H]
    float* WqPtT = WqGlT + (size_t)Hsz * Hsz;
    float* hb0   = WqPtT + (size_t)Hsz * Hsz;
    float* hb1   = hb0 + (size_t)Bsz * Hsz;
    float* cb0   = hb1 + (size_t)Bsz * Hsz;
    float* cb1   = cb0 + (size_t)Bsz * Hsz;
    float* gb    = cb1 + (size_t)Bsz * Hsz;
    float* dec   = gb  + (size_t)Bsz * Hsz;
    int*   mask  = (int*)(dec + (size_t)Bsz * Esz);       // [B,L]

    float* hbuf[2] = {hb0, hb1};
    float* cbuf[2] = {cb0, cb1};

    init_kernel<<<dim3(Bsz), dim3(256), 0, stream>>>(decoder_input, dec, mask);
    transpose_wq<<<dim3(256, 2), dim3(256), 0, stream>>>(glWq, ptWq, WqGlT, WqPtT);

    dim3 ge(Lsz * Bsz / 64, Hsz / 64);
    eproj_kernel<<<ge, dim3(256), 0, stream>>>(context, glWref, glbref, e_gl);
    eproj_kernel<<<ge, dim3(256), 0, stream>>>(context, ptWref, ptbref, e_pt);

    for (int t = 0; t < Lsz; t++) {
        const float* hin = (t == 0) ? h0 : hbuf[(t + 1) & 1];
        const float* cin = (t == 0) ? c0 : cbuf[(t + 1) & 1];
        float* hout = hbuf[t & 1];
        float* cout = cbuf[t & 1];

        lstm_fused<<<dim3(16, 16), dim3(256), 0, stream>>>(
            dec, hin, cin, Wih, Whh, bih, bhh, hout, cout);

        attn_kernel<false><<<dim3(Bsz), dim3(256), 0, stream>>>(
            hout, WqGlT, glbq, e_gl, glv, mask, gb, nullptr, t, nullptr, nullptr);

        attn_kernel<true><<<dim3(Bsz), dim3(256), 0, stream>>>(
            gb, WqPtT, ptbq, e_pt, ptv, mask, nullptr, out, t, dec, emb);
    }
}